// Round 15
// baseline (335.968 us; speedup 1.0000x reference)
//
#include <hip/hip_runtime.h>

// Problem constants
#define BB  4
#define SS  2048
#define DD  1024
#define HH  16
#define DHH 64
#define LOG2E 1.44269504088896340736f

typedef __attribute__((ext_vector_type(8)))  _Float16 half8;
typedef __attribute__((ext_vector_type(4)))  _Float16 half4;
typedef __attribute__((ext_vector_type(2)))  float    f32x2;
typedef __attribute__((ext_vector_type(4)))  float    f32x4;
typedef __attribute__((ext_vector_type(8)))  float    f32x8;
typedef __attribute__((ext_vector_type(16))) float    f32x16;
typedef __attribute__((ext_vector_type(4)))  unsigned int uint4v;

// exp2 via intrinsic ONLY: v_exp_f32 is a TRANS-class op with a required
// destination-read wait state; the compiler must see the producer to insert
// it. Inline-asm v_exp_f32 raced (R5/R6 failures).
#if __has_builtin(__builtin_amdgcn_exp2f)
#define EXP2(x) __builtin_amdgcn_exp2f(x)
#else
#define EXP2(x) exp2f(x)
#endif

// sign-extended single-bit extract: v_bfe_i32 (1 instr)
#if __has_builtin(__builtin_amdgcn_sbfe)
#define SBIT(x, p) __builtin_amdgcn_sbfe((int)(x), (unsigned)(p), 1u)
#else
#define SBIT(x, p) (((int)((x) << (31 - (p)))) >> 31)
#endif

// async global->LDS, 16B per lane; LDS dest = wave-uniform base + lane*16
__device__ __forceinline__ void gload_lds16(const void* g, void* l) {
  __builtin_amdgcn_global_load_lds(
      (const __attribute__((address_space(1))) unsigned int*)g,
      (__attribute__((address_space(3))) unsigned int*)l, 16, 0, 0);
}

// fp32->fp16 staging: load 8 floats, RTE-convert (bit-identical to the old
// cvt_in3 + gload path), ds_write_b128 to the SAME linear LDS slot that
// gload_lds16 would fill (chunk base + lane*8 halves). Source addressing is
// the same pre-swizzled col, so LDS contents are identical -> reads unchanged.
__device__ __forceinline__ void stage_cvt8(const float* g, _Float16* lds_chunk, int l) {
  float4 a = *(const float4*)g;
  float4 b = *(const float4*)(g + 4);
  half8 h;
  h[0] = (_Float16)a.x; h[1] = (_Float16)a.y;
  h[2] = (_Float16)a.z; h[3] = (_Float16)a.w;
  h[4] = (_Float16)b.x; h[5] = (_Float16)b.y;
  h[6] = (_Float16)b.z; h[7] = (_Float16)b.w;
  *(half8*)(lds_chunk + l * 8) = h;
}

// permlane32_swap halves-exchange helpers
__device__ __forceinline__ void plswap(unsigned int& x, unsigned int& y) {
  auto r = __builtin_amdgcn_permlane32_swap(x, y, false, false);
  x = r[0]; y = r[1];
}
__device__ __forceinline__ float xhalf_sum(float v) {
  unsigned int x = __builtin_bit_cast(unsigned int, v), y = x;
  plswap(x, y);
  return __builtin_bit_cast(float, x) + __builtin_bit_cast(float, y);
}

// in-lane tree sum of 8 f32
__device__ __forceinline__ float tree8(f32x8 u) {
  f32x4 v = __builtin_shufflevector(u, u, 0, 1, 2, 3) +
            __builtin_shufflevector(u, u, 4, 5, 6, 7);
  f32x2 w2 = __builtin_shufflevector(v, v, 0, 1) + __builtin_shufflevector(v, v, 2, 3);
  return w2[0] + w2[1];
}

// ---------------- fp32 -> fp16 convert (vectorized; fallback path) ----------
__global__ __launch_bounds__(256) void cvt_f32_f16(
    const float* __restrict__ in, _Float16* __restrict__ out, int n4) {
  int i = blockIdx.x * 256 + threadIdx.x;
  if (i >= n4) return;
  float4 a = reinterpret_cast<const float4*>(in)[i];
  half4 h;
  h[0] = (_Float16)a.x; h[1] = (_Float16)a.y;
  h[2] = (_Float16)a.z; h[3] = (_Float16)a.w;
  reinterpret_cast<half4*>(out)[i] = h;
}

// 4 weight matrices in one launch (blockIdx.y selects)
__global__ __launch_bounds__(256) void cvt_w4(
    const float* __restrict__ s0, const float* __restrict__ s1,
    const float* __restrict__ s2, const float* __restrict__ s3,
    _Float16* __restrict__ d0, _Float16* __restrict__ d1,
    _Float16* __restrict__ d2, _Float16* __restrict__ d3, int n4) {
  int i = blockIdx.x * 256 + threadIdx.x;
  if (i >= n4) return;
  const float* s; _Float16* d;
  switch (blockIdx.y) {
    case 0: s = s0; d = d0; break;
    case 1: s = s1; d = d1; break;
    case 2: s = s2; d = d2; break;
    default: s = s3; d = d3; break;
  }
  float4 a = reinterpret_cast<const float4*>(s)[i];
  half4 h;
  h[0] = (_Float16)a.x; h[1] = (_Float16)a.y;
  h[2] = (_Float16)a.z; h[3] = (_Float16)a.w;
  reinterpret_cast<half4*>(d)[i] = h;
}

// ---------------- mask int32 -> TRANSPOSED bitmask [b][kt][q] (1 = masked) ----
__global__ __launch_bounds__(256) void pack_mask_kernel(
    const int* __restrict__ m, unsigned long long* __restrict__ bitsT) {
  size_t g = (size_t)blockIdx.x * 256 + threadIdx.x;
  unsigned long long bal = __ballot(m[g] != 0);
  if ((threadIdx.x & 63) == 0) {
    int key = (int)(g & (SS - 1));
    int q   = (int)((g >> 11) & (SS - 1));
    int b   = (int)(g >> 22);
    bitsT[((size_t)(b * (SS / 64) + (key >> 6))) * SS + q] = bal;
  }
}

// ================= GEMM core =================
// NT GEMM: C[i][j] = sum_k A[i][k]*B[j][k], 128x128 tile, BK=64, 4 waves,
// 16x16x32 f16 MFMA, XOR swizzle. CVTA/CVTB: that operand is fp32 in global
// and is RTE-converted during staging (reg-staged); otherwise gload_lds.
template <bool CVTA, bool CVTB>
__device__ __forceinline__ void gemm_core(
    const void* __restrict__ Ablk, const void* __restrict__ Bblk, int K,
    int w, int l, _Float16* lsA, _Float16* lsB, f32x4 (&acc)[4][4]) {
  const int l15 = l & 15, l4 = l >> 4;
  const int wm = (w >> 1) * 64, wn = (w & 1) * 64;
  const int srow = l >> 3;
  const int scolh = ((l & 7) ^ srow) * 8;

  for (int kt = 0; kt < K; kt += 64) {
#pragma unroll
    for (int i = 0; i < 4; ++i) {
      int c = w * 4 + i;
      int row = c * 8 + srow;
      if constexpr (CVTA) {
        stage_cvt8((const float*)Ablk + (size_t)row * K + kt + scolh,
                   lsA + c * 512, l);
      } else {
        gload_lds16((const _Float16*)Ablk + (size_t)row * K + kt + scolh,
                    lsA + c * 512);
      }
      if constexpr (CVTB) {
        stage_cvt8((const float*)Bblk + (size_t)row * K + kt + scolh,
                   lsB + c * 512, l);
      } else {
        gload_lds16((const _Float16*)Bblk + (size_t)row * K + kt + scolh,
                    lsB + c * 512);
      }
    }
    __syncthreads();
#pragma unroll
    for (int kk = 0; kk < 2; ++kk) {
      half8 aF[4], bF[4];
#pragma unroll
      for (int x = 0; x < 4; ++x) {
        int ra = wm + x * 16 + l15;
        aF[x] = *(const half8*)(lsA + ra * 64 + ((kk * 32 + l4 * 8) ^ ((ra & 7) * 8)));
        int rb = wn + x * 16 + l15;
        bF[x] = *(const half8*)(lsB + rb * 64 + ((kk * 32 + l4 * 8) ^ ((rb & 7) * 8)));
      }
#pragma unroll
      for (int x = 0; x < 4; ++x)
#pragma unroll
        for (int y = 0; y < 4; ++y)
          acc[x][y] = __builtin_amdgcn_mfma_f32_16x16x32_f16(aF[x], bF[y], acc[x][y], 0, 0, 0);
    }
    __syncthreads();
  }
}

// standalone template version (modes 0-3), all-fp16 operands; grid 512
template <int MODE>
__global__ __launch_bounds__(256, 3) void gemm_nt(
    const _Float16* __restrict__ A, const _Float16* __restrict__ Bm,
    const float* __restrict__ bias, void* __restrict__ out,
    int M, int N, int K, int tilesN) {
  __shared__ _Float16 lsA[128 * 64];
  __shared__ _Float16 lsB[128 * 64];
  const int t = threadIdx.x, w = t >> 6, l = t & 63;
  const int nb8 = gridDim.x >> 3;
  const int bidx = (blockIdx.x & 7) * nb8 + (blockIdx.x >> 3);
  const int tm = bidx / tilesN, tn = bidx % tilesN;
  f32x4 acc[4][4] = {};
  gemm_core<false, false>((const void*)(A + (size_t)(tm * 128) * K),
                          (const void*)(Bm + (size_t)(tn * 128) * K),
                          K, w, l, lsA, lsB, acc);
  const int l15 = l & 15, l4 = l >> 4;
  const int wm = (w >> 1) * 64, wn = (w & 1) * 64;
#pragma unroll
  for (int x = 0; x < 4; ++x) {
#pragma unroll
    for (int r = 0; r < 4; ++r) {
      int i = tm * 128 + wm + x * 16 + l4 * 4 + r;
#pragma unroll
      for (int y = 0; y < 4; ++y) {
        int j = tn * 128 + wn + y * 16 + l15;
        float v = acc[x][y][r];
        if (MODE == 0) {
          v = (v + bias[j]) * (0.125f * LOG2E);
          ((_Float16*)out)[(((size_t)(i >> 11) * HH + (j >> 6)) * SS + (i & (SS - 1))) * DHH + (j & 63)] =
              (_Float16)v;
        } else if (MODE == 1) {
          v = v + bias[j];
          ((_Float16*)out)[(((size_t)(i >> 11) * HH + (j >> 6)) * SS + (i & (SS - 1))) * DHH + (j & 63)] =
              (_Float16)v;
        } else if (MODE == 2) {
          v = v + bias[i];
          ((_Float16*)out)[((size_t)(j >> 11) * DD + i) * SS + (j & (SS - 1))] = (_Float16)v;
        } else {
          ((float*)out)[(size_t)i * N + j] = v + bias[j];
        }
      }
    }
  }
}

// co-resident Q+K projection reading fp32 activations DIRECTLY (cvt fused
// into A-staging). 1024 blocks, bidx>>9 selects the GEMM; halves are
// structurally identical. [R12: co-residency -7µs. R7/R13: do NOT fuse V.]
__global__ __launch_bounds__(256, 3) void gemm_qk(
    const float* __restrict__ q32, const float* __restrict__ k32,
    const _Float16* __restrict__ wq, const _Float16* __restrict__ wk,
    const float* __restrict__ bq, const float* __restrict__ bk,
    _Float16* __restrict__ qh, _Float16* __restrict__ kh) {
  __shared__ _Float16 lsA[128 * 64];
  __shared__ _Float16 lsB[128 * 64];
  const int t = threadIdx.x, w = t >> 6, l = t & 63;
  const int bidx = (blockIdx.x & 7) * 128 + (blockIdx.x >> 3);  // 1024 % 8 == 0
  const int half = bidx >> 9;  // 0 = Q, 1 = K
  const int hb = bidx & 511;
  const int tm = hb >> 3, tn = hb & 7;
  const float* A     = half ? k32 : q32;
  const _Float16* Bm = half ? wk : wq;
  const float* bias  = half ? bk : bq;
  _Float16* dst      = half ? kh : qh;
  const float scl    = half ? 1.0f : (0.125f * LOG2E);
  f32x4 acc[4][4] = {};
  gemm_core<true, false>((const void*)(A + (size_t)(tm * 128) * DD),
                         (const void*)(Bm + (size_t)(tn * 128) * DD),
                         DD, w, l, lsA, lsB, acc);
  const int l15 = l & 15, l4 = l >> 4;
  const int wm = (w >> 1) * 64, wn = (w & 1) * 64;
#pragma unroll
  for (int x = 0; x < 4; ++x) {
#pragma unroll
    for (int r = 0; r < 4; ++r) {
      int i = tm * 128 + wm + x * 16 + l4 * 4 + r;
#pragma unroll
      for (int y = 0; y < 4; ++y) {
        int j = tn * 128 + wn + y * 16 + l15;
        float v = (acc[x][y][r] + bias[j]) * scl;
        dst[(((size_t)(i >> 11) * HH + (j >> 6)) * SS + (i & (SS - 1))) * DHH + (j & 63)] =
            (_Float16)v;
      }
    }
  }
}

// V projection reading fp32 value DIRECTLY (cvt fused into B-staging).
// A = Wv (fp16), B = value (fp32); out vt [B,H,DH,S]. grid 512.
__global__ __launch_bounds__(256, 3) void gemm_v(
    const _Float16* __restrict__ wv, const float* __restrict__ v32,
    const float* __restrict__ bv, _Float16* __restrict__ vt) {
  __shared__ _Float16 lsA[128 * 64];
  __shared__ _Float16 lsB[128 * 64];
  const int t = threadIdx.x, w = t >> 6, l = t & 63;
  const int bidx = (blockIdx.x & 7) * 64 + (blockIdx.x >> 3);  // 512 % 8 == 0
  const int tm = bidx >> 6, tn = bidx & 63;  // M = DD (8 tiles), N = B*S (64)
  f32x4 acc[4][4] = {};
  gemm_core<false, true>((const void*)(wv + (size_t)(tm * 128) * DD),
                         (const void*)(v32 + (size_t)(tn * 128) * DD),
                         DD, w, l, lsA, lsB, acc);
  const int l15 = l & 15, l4 = l >> 4;
  const int wm = (w >> 1) * 64, wn = (w & 1) * 64;
#pragma unroll
  for (int x = 0; x < 4; ++x) {
#pragma unroll
    for (int r = 0; r < 4; ++r) {
      int i = tm * 128 + wm + x * 16 + l4 * 4 + r;
#pragma unroll
      for (int y = 0; y < 4; ++y) {
        int j = tn * 128 + wn + y * 16 + l15;
        float v = acc[x][y][r] + bv[i];
        vt[((size_t)(j >> 11) * DD + i) * SS + (j & (SS - 1))] = (_Float16)v;
      }
    }
  }
}

// ---------------- flash attention, 32x32 MFMA, swapped QK^T ----------------
// (frozen since R10: 100 µs, MfmaUtil 30%, VALUBusy 63%, occ 32%)
__global__ __launch_bounds__(256, 4) void attn_kernel(
    const _Float16* __restrict__ qh, const _Float16* __restrict__ kh,
    const _Float16* __restrict__ vt, const unsigned long long* __restrict__ mT,
    _Float16* __restrict__ ctx) {
  __shared__ _Float16 lsK[2][64 * 64];
  __shared__ _Float16 lsV[2][64 * 64];

  const int t = threadIdx.x;
  const int w = t >> 6, l = t & 63;
  const int l31 = l & 31, hi = l >> 5;
  const int srow = l >> 3;
  const int scolh = ((l & 7) ^ srow) * 8;

  const int bid = ((blockIdx.x & 7) << 7) | (blockIdx.x >> 3);  // XCD swizzle (1024 % 8 == 0)
  const int bh = bid >> 4;
  const int qt = bid & 15;
  const int b = bh >> 4;
  const int h = bh & 15;
  const int qbase = qt * 128 + w * 32;

  // Q B-fragments (registers; wave owns 32 q-rows)
  const _Float16* qrow = qh + ((size_t)bh * SS + qbase + l31) * DHH + hi * 8;
  half8 bQ[4];
#pragma unroll
  for (int s = 0; s < 4; ++s) bQ[s] = *(const half8*)(qrow + s * 16);

  const _Float16* kbh = kh + (size_t)bh * SS * DHH;
  const _Float16* vbh = vt + (size_t)bh * DHH * SS;

  // loop-invariant swizzled LDS byte offsets
  int boff[2][4];
  {
    const int swzb = (l31 & 7) * 16;
#pragma unroll
    for (int i = 0; i < 2; ++i)
#pragma unroll
      for (int s = 0; s < 4; ++s)
        boff[i][s] = (i * 32 + l31) * 128 + (((s * 16 + hi * 8) * 2) ^ swzb);
  }

  // staging source element offsets (advance per tile)
  int ko0 = (w * 16 + srow) * DHH + scolh;
  int ko1 = ko0 + 8 * DHH;
  int vo0 = (w * 16 + srow) * SS + scolh;
  int vo1 = vo0 + 8 * SS;
  char* lsKb = (char*)&lsK[0][0];
  char* lsVb = (char*)&lsV[0][0];
  const int ldsb = w * 2048;  // this wave's LDS chunk byte base

  f32x16 o0 = {}, o1 = {};
  f32x8 lsum8 = {};

  const unsigned long long* mp = mT + (size_t)b * (SS / 64) * SS + qbase + l31;
  unsigned long long mb = mp[0];

  // prologue: stage tile 0 into buffer 0
  gload_lds16(kbh + ko0, lsKb + ldsb);
  gload_lds16(kbh + ko1, lsKb + ldsb + 1024);
  gload_lds16(vbh + vo0, lsVb + ldsb);
  gload_lds16(vbh + vo1, lsVb + ldsb + 1024);
  ko0 += 64 * DHH; ko1 += 64 * DHH; vo0 += 64; vo1 += 64;

#pragma unroll 1
  for (int kt = 0; kt < 32; ++kt) {
    const int curb = (kt & 1) << 13;  // *8192
    const int othb = curb ^ 8192;
    __syncthreads();  // staging(cur) complete, prev compute done
    if (kt < 31) {
      gload_lds16(kbh + ko0, lsKb + othb + ldsb);
      gload_lds16(kbh + ko1, lsKb + othb + ldsb + 1024);
      gload_lds16(vbh + vo0, lsVb + othb + ldsb);
      gload_lds16(vbh + vo1, lsVb + othb + ldsb + 1024);
      ko0 += 64 * DHH; ko1 += 64 * DHH; vo0 += 64; vo1 += 64;
    }
    unsigned long long mbn = 0;
    if (kt < 31) mbn = mp[(size_t)(kt + 1) * SS];

    const unsigned int mw0 = ((unsigned int)mb) >> (hi * 4);
    const unsigned int mw1 = ((unsigned int)(mb >> 32)) >> (hi * 4);
    const char* kbase = lsKb + curb;
    const char* vbase = lsVb + curb;

#pragma unroll
    for (int ns = 0; ns < 2; ++ns) {
      const unsigned int mwx = ns ? mw1 : mw0;
      // C-init: masked -> -inf, kept -> 0 (v_bfe_i32 + v_and = 2 ops/elem)
      f32x16 sc;
#pragma unroll
      for (int r = 0; r < 16; ++r) {
        const int p = (r & 3) + 8 * (r >> 2);
        sc[r] = __builtin_bit_cast(float,
            ((unsigned int)SBIT(mwx, p)) & 0xFF800000u);
      }
      // QK^T for this key-half (builtin MFMA: compiler manages hazards)
      __builtin_amdgcn_s_setprio(1);
#pragma unroll
      for (int s = 0; s < 4; ++s) {
        half8 aK = *(const half8*)(kbase + boff[ns][s]);
        sc = __builtin_amdgcn_mfma_f32_32x32x16_f16(aK, bQ[s], sc, 0, 0, 0);
      }
      __builtin_amdgcn_s_setprio(0);
      // softmax: each sc element read once; results stay in VGPRs
#pragma unroll
      for (int hf = 0; hf < 2; ++hf) {
        const int e = hf * 8;
        float e0 = EXP2(sc[e + 0]);
        float e1 = EXP2(sc[e + 1]);
        float e2 = EXP2(sc[e + 2]);
        float e3 = EXP2(sc[e + 3]);
        float e4 = EXP2(sc[e + 4]);
        float e5 = EXP2(sc[e + 5]);
        float e6 = EXP2(sc[e + 6]);
        float e7 = EXP2(sc[e + 7]);
        lsum8[0] += e0; lsum8[1] += e1; lsum8[2] += e2; lsum8[3] += e3;
        lsum8[4] += e4; lsum8[5] += e5; lsum8[6] += e6; lsum8[7] += e7;
        unsigned int pa = __builtin_bit_cast(unsigned int,
            __builtin_amdgcn_cvt_pkrtz(e0, e1));
        unsigned int pb = __builtin_bit_cast(unsigned int,
            __builtin_amdgcn_cvt_pkrtz(e2, e3));
        unsigned int pc = __builtin_bit_cast(unsigned int,
            __builtin_amdgcn_cvt_pkrtz(e4, e5));
        unsigned int pd = __builtin_bit_cast(unsigned int,
            __builtin_amdgcn_cvt_pkrtz(e6, e7));
        plswap(pa, pc);
        plswap(pb, pd);
        uint4v u4 = {pa, pb, pc, pd};
        half8 aP = __builtin_bit_cast(half8, u4);
        const int s = ns * 2 + hf;
        half8 bV0 = *(const half8*)(vbase + boff[0][s]);
        half8 bV1 = *(const half8*)(vbase + boff[1][s]);
        __builtin_amdgcn_s_setprio(1);
        o0 = __builtin_amdgcn_mfma_f32_32x32x16_f16(aP, bV0, o0, 0, 0, 0);
        o1 = __builtin_amdgcn_mfma_f32_32x32x16_f16(aP, bV1, o1, 0, 0, 0);
        __builtin_amdgcn_s_setprio(0);
      }
    }
    mb = mbn;
  }

  // ---- normalize + write ctx [B,S,D] fp16 ----
  const float lrun = xhalf_sum(tree8(lsum8));
  const float inv = 1.0f / lrun;
  _Float16* cbase = ctx + ((size_t)b * SS + qbase) * DD + h * DHH + l31;
#pragma unroll
  for (int r = 0; r < 16; ++r) {
    const int qr = (r & 3) + 8 * (r >> 2) + hi * 4;
    float ir = __shfl(inv, qr);
    cbase[(size_t)qr * DD]      = (_Float16)(o0[r] * ir);
    cbase[(size_t)qr * DD + 32] = (_Float16)(o1[r] * ir);
  }
}

// ---------------- launch ----------------
extern "C" void kernel_launch(void* const* d_in, const int* in_sizes, int n_in,
                              void* d_out, int out_size, void* d_ws, size_t ws_size,
                              hipStream_t stream) {
  const float* key   = (const float*)d_in[0];
  const float* value = (const float*)d_in[1];
  const float* query = (const float*)d_in[2];
  const int*   mask  = (const int*)d_in[3];
  const float* Wq = (const float*)d_in[4];
  const float* bq = (const float*)d_in[5];
  const float* Wk = (const float*)d_in[6];
  const float* bk = (const float*)d_in[7];
  const float* Wv = (const float*)d_in[8];
  const float* bv = (const float*)d_in[9];
  const float* Wo = (const float*)d_in[10];
  const float* bo = (const float*)d_in[11];
  float* out = (float*)d_out;

  char* ws = (char*)d_ws;
  const int n4_in = BB * SS * DD / 4;
  const int n4_w  = DD * DD / 4;
  const size_t MB = 1048576;

  if (ws_size >= 80 * MB) {
    // fused-cvt path: GEMMs read fp32 activations directly
    _Float16* wq16 = (_Float16*)(ws);
    _Float16* wk16 = (_Float16*)(ws + 2 * MB);
    _Float16* wv16 = (_Float16*)(ws + 4 * MB);
    _Float16* wo16 = (_Float16*)(ws + 6 * MB);
    _Float16* qh   = (_Float16*)(ws + 8 * MB);
    _Float16* kh   = (_Float16*)(ws + 24 * MB);
    _Float16* vt   = (_Float16*)(ws + 40 * MB);
    _Float16* ctx  = (_Float16*)(ws + 56 * MB);
    unsigned long long* mbitsT = (unsigned long long*)(ws + 72 * MB);

    pack_mask_kernel<<<BB * SS * SS / 64 / 4, 256, 0, stream>>>(mask, mbitsT);
    cvt_w4<<<dim3(n4_w / 256, 4), 256, 0, stream>>>(Wq, Wk, Wv, Wo, wq16, wk16, wv16, wo16, n4_w);
    gemm_qk<<<1024, 256, 0, stream>>>(query, key, wq16, wk16, bq, bk, qh, kh);
    gemm_v<<<512, 256, 0, stream>>>(wv16, value, bv, vt);
    attn_kernel<<<BB * HH * (SS / 128), 256, 0, stream>>>(qh, kh, vt, mbitsT, ctx);
    gemm_nt<3><<<512, 256, 0, stream>>>(ctx, wo16, bo, out, BB * SS, DD, DD, DD / 128);
  } else {
    // sequential fallback (R4 layout)
    _Float16* x16  = (_Float16*)(ws);
    _Float16* wq16 = (_Float16*)(ws + 16777216);
    _Float16* wk16 = (_Float16*)(ws + 18874368);
    _Float16* wv16 = (_Float16*)(ws + 20971520);
    _Float16* wo16 = (_Float16*)(ws + 23068672);
    _Float16* qh   = (_Float16*)(ws + 25165824);
    _Float16* kh   = (_Float16*)(ws + 41943040);
    _Float16* vt   = (_Float16*)(ws + 58720256);
    unsigned long long* mbitsT = (unsigned long long*)(ws + 75497472);
    _Float16* ctx = x16;

    pack_mask_kernel<<<BB * SS * SS / 64 / 4, 256, 0, stream>>>(mask, mbitsT);
    cvt_w4<<<dim3(n4_w / 256, 4), 256, 0, stream>>>(Wq, Wk, Wv, Wo, wq16, wk16, wv16, wo16, n4_w);
    cvt_f32_f16<<<n4_in / 256, 256, 0, stream>>>(query, x16, n4_in);
    gemm_nt<0><<<512, 256, 0, stream>>>(x16, wq16, bq, qh, BB * SS, DD, DD, DD / 128);
    cvt_f32_f16<<<n4_in / 256, 256, 0, stream>>>(key, x16, n4_in);
    gemm_nt<1><<<512, 256, 0, stream>>>(x16, wk16, bk, kh, BB * SS, DD, DD, DD / 128);
    cvt_f32_f16<<<n4_in / 256, 256, 0, stream>>>(value, x16, n4_in);
    gemm_nt<2><<<512, 256, 0, stream>>>(wv16, x16, bv, vt, DD, BB * SS, DD, BB * SS / 128);
    attn_kernel<<<BB * HH * (SS / 128), 256, 0, stream>>>(qh, kh, vt, mbitsT, ctx);
    gemm_nt<3><<<512, 256, 0, stream>>>(ctx, wo16, bo, out, BB * SS, DD, DD, DD / 128);
  }
}

// Round 16
// 258.133 us; speedup vs baseline: 1.3015x; 1.3015x over previous
//
#include <hip/hip_runtime.h>

// Problem constants
#define BB  4
#define SS  2048
#define DD  1024
#define HH  16
#define DHH 64
#define LOG2E 1.44269504088896340736f

typedef __attribute__((ext_vector_type(8)))  _Float16 half8;
typedef __attribute__((ext_vector_type(4)))  _Float16 half4;
typedef __attribute__((ext_vector_type(2)))  float    f32x2;
typedef __attribute__((ext_vector_type(4)))  float    f32x4;
typedef __attribute__((ext_vector_type(8)))  float    f32x8;
typedef __attribute__((ext_vector_type(16))) float    f32x16;
typedef __attribute__((ext_vector_type(4)))  unsigned int uint4v;

// exp2 via intrinsic ONLY: v_exp_f32 is a TRANS-class op with a required
// destination-read wait state; the compiler must see the producer to insert
// it. Inline-asm v_exp_f32 raced (R5/R6 failures).
#if __has_builtin(__builtin_amdgcn_exp2f)
#define EXP2(x) __builtin_amdgcn_exp2f(x)
#else
#define EXP2(x) exp2f(x)
#endif

// sign-extended single-bit extract: v_bfe_i32 (1 instr)
#if __has_builtin(__builtin_amdgcn_sbfe)
#define SBIT(x, p) __builtin_amdgcn_sbfe((int)(x), (unsigned)(p), 1u)
#else
#define SBIT(x, p) (((int)((x) << (31 - (p)))) >> 31)
#endif

// async global->LDS, 16B per lane; LDS dest = wave-uniform base + lane*16
// [R15 lesson: do NOT replace with reg-staged cvt — serial load->wait->write
// chain collapses MfmaUtil to 9%; gload_lds's async DMA queue is the win.]
__device__ __forceinline__ void gload_lds16(const void* g, void* l) {
  __builtin_amdgcn_global_load_lds(
      (const __attribute__((address_space(1))) unsigned int*)g,
      (__attribute__((address_space(3))) unsigned int*)l, 16, 0, 0);
}

// permlane32_swap halves-exchange helpers
__device__ __forceinline__ void plswap(unsigned int& x, unsigned int& y) {
  auto r = __builtin_amdgcn_permlane32_swap(x, y, false, false);
  x = r[0]; y = r[1];
}
__device__ __forceinline__ float xhalf_sum(float v) {
  unsigned int x = __builtin_bit_cast(unsigned int, v), y = x;
  plswap(x, y);
  return __builtin_bit_cast(float, x) + __builtin_bit_cast(float, y);
}

// in-lane tree sum of 8 f32
__device__ __forceinline__ float tree8(f32x8 u) {
  f32x4 v = __builtin_shufflevector(u, u, 0, 1, 2, 3) +
            __builtin_shufflevector(u, u, 4, 5, 6, 7);
  f32x2 w2 = __builtin_shufflevector(v, v, 0, 1) + __builtin_shufflevector(v, v, 2, 3);
  return w2[0] + w2[1];
}

// ---------------- fp32 -> fp16 convert (vectorized) ----------------
__global__ __launch_bounds__(256) void cvt_f32_f16(
    const float* __restrict__ in, _Float16* __restrict__ out, int n4) {
  int i = blockIdx.x * 256 + threadIdx.x;
  if (i >= n4) return;
  float4 a = reinterpret_cast<const float4*>(in)[i];
  half4 h;
  h[0] = (_Float16)a.x; h[1] = (_Float16)a.y;
  h[2] = (_Float16)a.z; h[3] = (_Float16)a.w;
  reinterpret_cast<half4*>(out)[i] = h;
}

// 3 input tensors in one launch (blockIdx.y selects)
__global__ __launch_bounds__(256) void cvt_in3(
    const float* __restrict__ s0, const float* __restrict__ s1,
    const float* __restrict__ s2,
    _Float16* __restrict__ d0, _Float16* __restrict__ d1,
    _Float16* __restrict__ d2, int n4) {
  int i = blockIdx.x * 256 + threadIdx.x;
  if (i >= n4) return;
  const float* s; _Float16* d;
  switch (blockIdx.y) {
    case 0: s = s0; d = d0; break;
    case 1: s = s1; d = d1; break;
    default: s = s2; d = d2; break;
  }
  float4 a = reinterpret_cast<const float4*>(s)[i];
  half4 h;
  h[0] = (_Float16)a.x; h[1] = (_Float16)a.y;
  h[2] = (_Float16)a.z; h[3] = (_Float16)a.w;
  reinterpret_cast<half4*>(d)[i] = h;
}

// 4 weight matrices in one launch (blockIdx.y selects)
__global__ __launch_bounds__(256) void cvt_w4(
    const float* __restrict__ s0, const float* __restrict__ s1,
    const float* __restrict__ s2, const float* __restrict__ s3,
    _Float16* __restrict__ d0, _Float16* __restrict__ d1,
    _Float16* __restrict__ d2, _Float16* __restrict__ d3, int n4) {
  int i = blockIdx.x * 256 + threadIdx.x;
  if (i >= n4) return;
  const float* s; _Float16* d;
  switch (blockIdx.y) {
    case 0: s = s0; d = d0; break;
    case 1: s = s1; d = d1; break;
    case 2: s = s2; d = d2; break;
    default: s = s3; d = d3; break;
  }
  float4 a = reinterpret_cast<const float4*>(s)[i];
  half4 h;
  h[0] = (_Float16)a.x; h[1] = (_Float16)a.y;
  h[2] = (_Float16)a.z; h[3] = (_Float16)a.w;
  reinterpret_cast<half4*>(d)[i] = h;
}

// ---------------- mask int32 -> TRANSPOSED bitmask [b][kt][q] (1 = masked) ----
__global__ __launch_bounds__(256) void pack_mask_kernel(
    const int* __restrict__ m, unsigned long long* __restrict__ bitsT) {
  size_t g = (size_t)blockIdx.x * 256 + threadIdx.x;
  unsigned long long bal = __ballot(m[g] != 0);
  if ((threadIdx.x & 63) == 0) {
    int key = (int)(g & (SS - 1));
    int q   = (int)((g >> 11) & (SS - 1));
    int b   = (int)(g >> 22);
    bitsT[((size_t)(b * (SS / 64) + (key >> 6))) * SS + q] = bal;
  }
}

// ================= GEMM cores =================
// NT GEMM body: C[i][j] = sum_k A[i][k]*B[j][k], 128x128 tile, BK=64,
// 4 waves, 16x16x32 f16 MFMA, global_load_lds + XOR swizzle. (R10-proven.)

#define GEMM_BODY(A, Bm, K)                                                       \
  __shared__ _Float16 lsA[128 * 64];                                              \
  __shared__ _Float16 lsB[128 * 64];                                              \
  const int t = threadIdx.x;                                                      \
  const int w = t >> 6, l = t & 63;                                               \
  const int l15 = l & 15, l4 = l >> 4;                                            \
  const int wm = (w >> 1) * 64, wn = (w & 1) * 64;                                \
  const int srow = l >> 3;                                                        \
  const int scolh = ((l & 7) ^ srow) * 8;                                         \
  f32x4 acc[4][4] = {};                                                           \
  const _Float16* gA = (A) + (size_t)(tm * 128) * (K);                            \
  const _Float16* gB = (Bm) + (size_t)(tn * 128) * (K);                           \
  for (int kt = 0; kt < (K); kt += 64) {                                          \
    _Pragma("unroll") for (int i = 0; i < 4; ++i) {                               \
      int c = w * 4 + i;                                                          \
      int row = c * 8 + srow;                                                     \
      gload_lds16(gA + (size_t)row * (K) + kt + scolh, lsA + c * 512);            \
      gload_lds16(gB + (size_t)row * (K) + kt + scolh, lsB + c * 512);            \
    }                                                                             \
    __syncthreads();                                                              \
    _Pragma("unroll") for (int kk = 0; kk < 2; ++kk) {                            \
      half8 aF[4], bF[4];                                                         \
      _Pragma("unroll") for (int x = 0; x < 4; ++x) {                             \
        int ra = wm + x * 16 + l15;                                               \
        aF[x] = *(const half8*)(lsA + ra * 64 + ((kk * 32 + l4 * 8) ^ ((ra & 7) * 8))); \
        int rb = wn + x * 16 + l15;                                               \
        bF[x] = *(const half8*)(lsB + rb * 64 + ((kk * 32 + l4 * 8) ^ ((rb & 7) * 8))); \
      }                                                                           \
      _Pragma("unroll") for (int x = 0; x < 4; ++x)                               \
        _Pragma("unroll") for (int y = 0; y < 4; ++y)                             \
          acc[x][y] = __builtin_amdgcn_mfma_f32_16x16x32_f16(aF[x], bF[y], acc[x][y], 0, 0, 0); \
    }                                                                             \
    __syncthreads();                                                              \
  }

// standalone template version (modes 0-3); grid 512
template <int MODE>
__global__ __launch_bounds__(256, 3) void gemm_nt(
    const _Float16* __restrict__ A, const _Float16* __restrict__ Bm,
    const float* __restrict__ bias, void* __restrict__ out,
    int M, int N, int K, int tilesN) {
  const int nb8 = gridDim.x >> 3;
  const int bidx = (blockIdx.x & 7) * nb8 + (blockIdx.x >> 3);
  const int tm = bidx / tilesN, tn = bidx % tilesN;
  GEMM_BODY(A, Bm, K)
#pragma unroll
  for (int x = 0; x < 4; ++x) {
#pragma unroll
    for (int r = 0; r < 4; ++r) {
      int i = tm * 128 + wm + x * 16 + l4 * 4 + r;
#pragma unroll
      for (int y = 0; y < 4; ++y) {
        int j = tn * 128 + wn + y * 16 + l15;
        float v = acc[x][y][r];
        if (MODE == 0) {
          v = (v + bias[j]) * (0.125f * LOG2E);
          ((_Float16*)out)[(((size_t)(i >> 11) * HH + (j >> 6)) * SS + (i & (SS - 1))) * DHH + (j & 63)] =
              (_Float16)v;
        } else if (MODE == 1) {
          v = v + bias[j];
          ((_Float16*)out)[(((size_t)(i >> 11) * HH + (j >> 6)) * SS + (i & (SS - 1))) * DHH + (j & 63)] =
              (_Float16)v;
        } else if (MODE == 2) {
          v = v + bias[i];
          ((_Float16*)out)[((size_t)(j >> 11) * DD + i) * SS + (j & (SS - 1))] = (_Float16)v;
        } else {
          ((float*)out)[(size_t)i * N + j] = v + bias[j];
        }
      }
    }
  }
}

// co-resident Q+K projection: 1024 blocks, bidx>>9 selects the GEMM.
// Both halves are structurally IDENTICAL (tilesN=8, same epilogue layout);
// only {A, B, bias, dst, scale} differ -> minimal regalloc delta vs split.
// After XCD swizzle, XCDs 0-3 own Q and XCDs 4-7 own K (per-XCD L2 holds
// exactly one 2MB weight panel). [R12-proven: -7 µs vs split. 3-way QKV
// fusion regressed twice (R7 +8µs, R13 +9µs); fused-cvt staging regressed
// (R15 +77µs). Do not re-fuse V; do not reg-stage the cvt.]
__global__ __launch_bounds__(256, 3) void gemm_qk(
    const _Float16* __restrict__ xq, const _Float16* __restrict__ xk,
    const _Float16* __restrict__ wq, const _Float16* __restrict__ wk,
    const float* __restrict__ bq, const float* __restrict__ bk,
    _Float16* __restrict__ qh, _Float16* __restrict__ kh) {
  const int bidx = (blockIdx.x & 7) * 128 + (blockIdx.x >> 3);  // 1024 % 8 == 0
  const int half = bidx >> 9;  // 0 = Q, 1 = K
  const int hb = bidx & 511;
  const int tm = hb >> 3, tn = hb & 7;
  const _Float16* A  = half ? xk : xq;
  const _Float16* Bm = half ? wk : wq;
  const float* bias  = half ? bk : bq;
  _Float16* dst      = half ? kh : qh;
  const float scl    = half ? 1.0f : (0.125f * LOG2E);
  GEMM_BODY(A, Bm, DD)
#pragma unroll
  for (int x = 0; x < 4; ++x) {
#pragma unroll
    for (int r = 0; r < 4; ++r) {
      int i = tm * 128 + wm + x * 16 + l4 * 4 + r;
#pragma unroll
      for (int y = 0; y < 4; ++y) {
        int j = tn * 128 + wn + y * 16 + l15;
        float v = (acc[x][y][r] + bias[j]) * scl;
        dst[(((size_t)(i >> 11) * HH + (j >> 6)) * SS + (i & (SS - 1))) * DHH + (j & 63)] =
            (_Float16)v;
      }
    }
  }
}

// ---------------- flash attention, 32x32 MFMA, swapped QK^T ----------------
// (frozen since R10: 100 µs, MfmaUtil 30%, VALUBusy 63%, occ 32%)
__global__ __launch_bounds__(256, 4) void attn_kernel(
    const _Float16* __restrict__ qh, const _Float16* __restrict__ kh,
    const _Float16* __restrict__ vt, const unsigned long long* __restrict__ mT,
    _Float16* __restrict__ ctx) {
  __shared__ _Float16 lsK[2][64 * 64];
  __shared__ _Float16 lsV[2][64 * 64];

  const int t = threadIdx.x;
  const int w = t >> 6, l = t & 63;
  const int l31 = l & 31, hi = l >> 5;
  const int srow = l >> 3;
  const int scolh = ((l & 7) ^ srow) * 8;

  const int bid = ((blockIdx.x & 7) << 7) | (blockIdx.x >> 3);  // XCD swizzle (1024 % 8 == 0)
  const int bh = bid >> 4;
  const int qt = bid & 15;
  const int b = bh >> 4;
  const int h = bh & 15;
  const int qbase = qt * 128 + w * 32;

  // Q B-fragments (registers; wave owns 32 q-rows)
  const _Float16* qrow = qh + ((size_t)bh * SS + qbase + l31) * DHH + hi * 8;
  half8 bQ[4];
#pragma unroll
  for (int s = 0; s < 4; ++s) bQ[s] = *(const half8*)(qrow + s * 16);

  const _Float16* kbh = kh + (size_t)bh * SS * DHH;
  const _Float16* vbh = vt + (size_t)bh * DHH * SS;

  // loop-invariant swizzled LDS byte offsets
  int boff[2][4];
  {
    const int swzb = (l31 & 7) * 16;
#pragma unroll
    for (int i = 0; i < 2; ++i)
#pragma unroll
      for (int s = 0; s < 4; ++s)
        boff[i][s] = (i * 32 + l31) * 128 + (((s * 16 + hi * 8) * 2) ^ swzb);
  }

  // staging source element offsets (advance per tile)
  int ko0 = (w * 16 + srow) * DHH + scolh;
  int ko1 = ko0 + 8 * DHH;
  int vo0 = (w * 16 + srow) * SS + scolh;
  int vo1 = vo0 + 8 * SS;
  char* lsKb = (char*)&lsK[0][0];
  char* lsVb = (char*)&lsV[0][0];
  const int ldsb = w * 2048;  // this wave's LDS chunk byte base

  f32x16 o0 = {}, o1 = {};
  f32x8 lsum8 = {};

  const unsigned long long* mp = mT + (size_t)b * (SS / 64) * SS + qbase + l31;
  unsigned long long mb = mp[0];

  // prologue: stage tile 0 into buffer 0
  gload_lds16(kbh + ko0, lsKb + ldsb);
  gload_lds16(kbh + ko1, lsKb + ldsb + 1024);
  gload_lds16(vbh + vo0, lsVb + ldsb);
  gload_lds16(vbh + vo1, lsVb + ldsb + 1024);
  ko0 += 64 * DHH; ko1 += 64 * DHH; vo0 += 64; vo1 += 64;

#pragma unroll 1
  for (int kt = 0; kt < 32; ++kt) {
    const int curb = (kt & 1) << 13;  // *8192
    const int othb = curb ^ 8192;
    __syncthreads();  // staging(cur) complete, prev compute done
    if (kt < 31) {
      gload_lds16(kbh + ko0, lsKb + othb + ldsb);
      gload_lds16(kbh + ko1, lsKb + othb + ldsb + 1024);
      gload_lds16(vbh + vo0, lsVb + othb + ldsb);
      gload_lds16(vbh + vo1, lsVb + othb + ldsb + 1024);
      ko0 += 64 * DHH; ko1 += 64 * DHH; vo0 += 64; vo1 += 64;
    }
    unsigned long long mbn = 0;
    if (kt < 31) mbn = mp[(size_t)(kt + 1) * SS];

    const unsigned int mw0 = ((unsigned int)mb) >> (hi * 4);
    const unsigned int mw1 = ((unsigned int)(mb >> 32)) >> (hi * 4);
    const char* kbase = lsKb + curb;
    const char* vbase = lsVb + curb;

#pragma unroll
    for (int ns = 0; ns < 2; ++ns) {
      const unsigned int mwx = ns ? mw1 : mw0;
      // C-init: masked -> -inf, kept -> 0 (v_bfe_i32 + v_and = 2 ops/elem)
      f32x16 sc;
#pragma unroll
      for (int r = 0; r < 16; ++r) {
        const int p = (r & 3) + 8 * (r >> 2);
        sc[r] = __builtin_bit_cast(float,
            ((unsigned int)SBIT(mwx, p)) & 0xFF800000u);
      }
      // QK^T for this key-half (builtin MFMA: compiler manages hazards)
      __builtin_amdgcn_s_setprio(1);
#pragma unroll
      for (int s = 0; s < 4; ++s) {
        half8 aK = *(const half8*)(kbase + boff[ns][s]);
        sc = __builtin_amdgcn_mfma_f32_32x32x16_f16(aK, bQ[s], sc, 0, 0, 0);
      }
      __builtin_amdgcn_s_setprio(0);
      // softmax: each sc element read once; results stay in VGPRs
#pragma unroll
      for (int hf = 0; hf < 2; ++hf) {
        const int e = hf * 8;
        float e0 = EXP2(sc[e + 0]);
        float e1 = EXP2(sc[e + 1]);
        float e2 = EXP2(sc[e + 2]);
        float e3 = EXP2(sc[e + 3]);
        float e4 = EXP2(sc[e + 4]);
        float e5 = EXP2(sc[e + 5]);
        float e6 = EXP2(sc[e + 6]);
        float e7 = EXP2(sc[e + 7]);
        lsum8[0] += e0; lsum8[1] += e1; lsum8[2] += e2; lsum8[3] += e3;
        lsum8[4] += e4; lsum8[5] += e5; lsum8[6] += e6; lsum8[7] += e7;
        unsigned int pa = __builtin_bit_cast(unsigned int,
            __builtin_amdgcn_cvt_pkrtz(e0, e1));
        unsigned int pb = __builtin_bit_cast(unsigned int,
            __builtin_amdgcn_cvt_pkrtz(e2, e3));
        unsigned int pc = __builtin_bit_cast(unsigned int,
            __builtin_amdgcn_cvt_pkrtz(e4, e5));
        unsigned int pd = __builtin_bit_cast(unsigned int,
            __builtin_amdgcn_cvt_pkrtz(e6, e7));
        plswap(pa, pc);
        plswap(pb, pd);
        uint4v u4 = {pa, pb, pc, pd};
        half8 aP = __builtin_bit_cast(half8, u4);
        const int s = ns * 2 + hf;
        half8 bV0 = *(const half8*)(vbase + boff[0][s]);
        half8 bV1 = *(const half8*)(vbase + boff[1][s]);
        __builtin_amdgcn_s_setprio(1);
        o0 = __builtin_amdgcn_mfma_f32_32x32x16_f16(aP, bV0, o0, 0, 0, 0);
        o1 = __builtin_amdgcn_mfma_f32_32x32x16_f16(aP, bV1, o1, 0, 0, 0);
        __builtin_amdgcn_s_setprio(0);
      }
    }
    mb = mbn;
  }

  // ---- normalize + write ctx [B,S,D] fp16 ----
  const float lrun = xhalf_sum(tree8(lsum8));
  const float inv = 1.0f / lrun;
  _Float16* cbase = ctx + ((size_t)b * SS + qbase) * DD + h * DHH + l31;
#pragma unroll
  for (int r = 0; r < 16; ++r) {
    const int qr = (r & 3) + 8 * (r >> 2) + hi * 4;
    float ir = __shfl(inv, qr);
    cbase[(size_t)qr * DD]      = (_Float16)(o0[r] * ir);
    cbase[(size_t)qr * DD + 32] = (_Float16)(o1[r] * ir);
  }
}

// ---------------- launch ----------------
extern "C" void kernel_launch(void* const* d_in, const int* in_sizes, int n_in,
                              void* d_out, int out_size, void* d_ws, size_t ws_size,
                              hipStream_t stream) {
  const float* key   = (const float*)d_in[0];
  const float* value = (const float*)d_in[1];
  const float* query = (const float*)d_in[2];
  const int*   mask  = (const int*)d_in[3];
  const float* Wq = (const float*)d_in[4];
  const float* bq = (const float*)d_in[5];
  const float* Wk = (const float*)d_in[6];
  const float* bk = (const float*)d_in[7];
  const float* Wv = (const float*)d_in[8];
  const float* bv = (const float*)d_in[9];
  const float* Wo = (const float*)d_in[10];
  const float* bo = (const float*)d_in[11];
  float* out = (float*)d_out;

  char* ws = (char*)d_ws;
  const int n4_in = BB * SS * DD / 4;
  const int n4_w  = DD * DD / 4;
  const size_t MB = 1048576;

  if (ws_size >= 106 * MB) {
    // all three converted inputs live simultaneously
    _Float16* xq = (_Float16*)(ws);
    _Float16* xk = (_Float16*)(ws + 16 * MB);
    _Float16* xv = (_Float16*)(ws + 32 * MB);
    _Float16* wq16 = (_Float16*)(ws + 48 * MB);
    _Float16* wk16 = (_Float16*)(ws + 50 * MB);
    _Float16* wv16 = (_Float16*)(ws + 52 * MB);
    _Float16* wo16 = (_Float16*)(ws + 54 * MB);
    _Float16* qh = (_Float16*)(ws + 56 * MB);
    _Float16* kh = (_Float16*)(ws + 72 * MB);
    _Float16* vt = (_Float16*)(ws + 88 * MB);
    unsigned long long* mbitsT = (unsigned long long*)(ws + 104 * MB);
    _Float16* ctx = xq;  // xq free after QK GEMM

    pack_mask_kernel<<<BB * SS * SS / 64 / 4, 256, 0, stream>>>(mask, mbitsT);
    cvt_w4<<<dim3(n4_w / 256, 4), 256, 0, stream>>>(Wq, Wk, Wv, Wo, wq16, wk16, wv16, wo16, n4_w);
    cvt_in3<<<dim3(n4_in / 256, 3), 256, 0, stream>>>(query, key, value, xq, xk, xv, n4_in);
    gemm_qk<<<1024, 256, 0, stream>>>(xq, xk, wq16, wk16, bq, bk, qh, kh);
    gemm_nt<2><<<512, 256, 0, stream>>>(wv16, xv, bv, vt, DD, BB * SS, DD, BB * SS / 128);
    attn_kernel<<<BB * HH * (SS / 128), 256, 0, stream>>>(qh, kh, vt, mbitsT, ctx);
    gemm_nt<3><<<512, 256, 0, stream>>>(ctx, wo16, bo, out, BB * SS, DD, DD, DD / 128);
  } else {
    // sequential fallback (R4 layout)
    _Float16* x16  = (_Float16*)(ws);
    _Float16* wq16 = (_Float16*)(ws + 16777216);
    _Float16* wk16 = (_Float16*)(ws + 18874368);
    _Float16* wv16 = (_Float16*)(ws + 20971520);
    _Float16* wo16 = (_Float16*)(ws + 23068672);
    _Float16* qh   = (_Float16*)(ws + 25165824);
    _Float16* kh   = (_Float16*)(ws + 41943040);
    _Float16* vt   = (_Float16*)(ws + 58720256);
    unsigned long long* mbitsT = (unsigned long long*)(ws + 75497472);
    _Float16* ctx = x16;

    pack_mask_kernel<<<BB * SS * SS / 64 / 4, 256, 0, stream>>>(mask, mbitsT);
    cvt_w4<<<dim3(n4_w / 256, 4), 256, 0, stream>>>(Wq, Wk, Wv, Wo, wq16, wk16, wv16, wo16, n4_w);
    cvt_f32_f16<<<n4_in / 256, 256, 0, stream>>>(query, x16, n4_in);
    gemm_nt<0><<<512, 256, 0, stream>>>(x16, wq16, bq, qh, BB * SS, DD, DD, DD / 128);
    cvt_f32_f16<<<n4_in / 256, 256, 0, stream>>>(key, x16, n4_in);
    gemm_nt<1><<<512, 256, 0, stream>>>(x16, wk16, bk, kh, BB * SS, DD, DD, DD / 128);
    cvt_f32_f16<<<n4_in / 256, 256, 0, stream>>>(value, x16, n4_in);
    gemm_nt<2><<<512, 256, 0, stream>>>(wv16, x16, bv, vt, DD, BB * SS, DD, BB * SS / 128);
    attn_kernel<<<BB * HH * (SS / 128), 256, 0, stream>>>(qh, kh, vt, mbitsT, ctx);
    gemm_nt<3><<<512, 256, 0, stream>>>(ctx, wo16, bo, out, BB * SS, DD, DD, DD / 128);
  }
}